// Round 7
// baseline (635.119 us; speedup 1.0000x reference)
//
#include <hip/hip_runtime.h>
#include <hip/hip_bf16.h>

// Problem constants (from reference)
#define N_ENC 500000
#define N_PAT 100000
#define D 64
#define HID 128
#define NE 1000000
#define N_ALL 600000          // concatenated node space: enc [0,500K), pat [500K,600K)

typedef unsigned short ushort_t;
typedef unsigned int uint_t;
typedef __attribute__((ext_vector_type(8))) short bfrag8;   // 8 x bf16 (4 VGPRs)
typedef __attribute__((ext_vector_type(4))) float f32x4;

// Workspace layout (float units). Zeroed region first (one small memset).
#define OFF_HIST     0              // 600,000 ints (concatenated)
#define ZERO_FLOATS  600000         // 2.4 MB zeroed
#define OFF_EXCL     600000         // 600,000
#define OFF_PART     1200000        // 1024
#define OFF_BASE     1201024        // 600,001 (pad 600,032)
#define OFF_CUR      1801056        // 600,000
#define OFF_CSR      2401056        // 2,000,000 ints (pe edges [0,1M), ep [1M,2M))
#define OFF_XBF_ENC  4401056        // 500,000*64 bf16 = 16,000,000 floats
#define OFF_XBF_PAT  20401056       // 100,000*64 bf16 = 3,200,000 floats
#define OFF_SPAT     23601056       // 100,000
#define OFF_FRAGS    23701056       // 4 matrices * 8192 ushort = 16,384 floats
#define OFF_WL2C     23717440       // 128
#define OFF_WR2C     23717568       // 128
#define OFF_C0       23717696       // 64
// end ~23.72M floats ~94.9 MB

__device__ inline ushort_t f2bf(float x) {
    // round-to-nearest-even f32 -> bf16
    uint_t u = __float_as_uint(x);
    u += 0x7fffu + ((u >> 16) & 1u);
    return (ushort_t)(u >> 16);
}

// ---------------- Prep (weights -> MFMA fragments; layer-2 collapse) --------
__global__ __launch_bounds__(256) void prep_kernel(
    const float* __restrict__ Wl_pe1, const float* __restrict__ Wr_pe1,
    const float* __restrict__ Wl_ep1, const float* __restrict__ Wr_ep1,
    const float* __restrict__ Wl_pe2, const float* __restrict__ Wr_pe2,
    const float* __restrict__ b_pe2, const float* __restrict__ Wc,
    const float* __restrict__ bc, float* __restrict__ ws)
{
    int t = blockIdx.x * blockDim.x + threadIdx.x;
    const int total = 4 * 8192;
    ushort_t* fr = (ushort_t*)(ws + OFF_FRAGS);
    for (int i = t; i < total; i += gridDim.x * blockDim.x) {
        int mtx = i >> 13;
        int r = i & 8191;
        int jj = r & 7;
        int l = (r >> 3) & 63;
        int ft = r >> 9;          // 0..15 = jt*2+kt
        int kt = ft & 1;
        int jt = ft >> 1;
        int k = kt * 32 + (l >> 4) * 8 + jj;
        int j = jt * 16 + (l & 15);
        const float* W = (mtx == 0) ? Wl_pe1 : (mtx == 1) ? Wr_pe1
                       : (mtx == 2) ? Wl_ep1 : Wr_ep1;
        fr[i] = f2bf(W[k * HID + j]);
    }
    if (blockIdx.x == 0) {
        int tid = threadIdx.x;
        if (tid < HID) {
            float s1 = 0.f, s2 = 0.f;
            for (int j = 0; j < HID; j++) {
                float wc = Wc[j];
                s1 += Wl_pe2[tid * HID + j] * wc;
                s2 += Wr_pe2[tid * HID + j] * wc;
            }
            ws[OFF_WL2C + tid] = s1;
            ws[OFF_WR2C + tid] = s2;
            if (tid == 0) {
                float c0 = bc[0];
                for (int j = 0; j < HID; j++) c0 += b_pe2[j] * Wc[j];
                ws[OFF_C0] = c0;
            }
        }
    }
}

// f32 -> bf16 conversion for BOTH feature arrays, 8 elems/thread, one launch.
__global__ __launch_bounds__(256) void cvt_bf16_kernel(
    const float* __restrict__ xe, const float* __restrict__ xp,
    ushort_t* __restrict__ oe, ushort_t* __restrict__ op)
{
    const int n8e = N_ENC * D / 8;   // 4,000,000
    const int n8p = N_PAT * D / 8;   // 800,000
    int i = blockIdx.x * 256 + threadIdx.x;
    const float* in;
    ushort_t* out;
    size_t idx;
    if (i < n8e) { in = xe; out = oe; idx = (size_t)i * 8; }
    else {
        int j = i - n8e;
        if (j >= n8p) return;
        in = xp; out = op; idx = (size_t)j * 8;
    }
    const f32x4* p = (const f32x4*)(in + idx);
    f32x4 v0 = p[0], v1 = p[1];
    uint4 o;
    o.x = (uint_t)f2bf(v0[0]) | ((uint_t)f2bf(v0[1]) << 16);
    o.y = (uint_t)f2bf(v0[2]) | ((uint_t)f2bf(v0[3]) << 16);
    o.z = (uint_t)f2bf(v1[0]) | ((uint_t)f2bf(v1[1]) << 16);
    o.w = (uint_t)f2bf(v1[2]) | ((uint_t)f2bf(v1[3]) << 16);
    *(uint4*)(out + idx) = o;
}

// ---------------- CSR build over concatenated node space --------------------

__global__ __launch_bounds__(256) void hist_kernel(
    const int* __restrict__ dst_pe, const int* __restrict__ dst_ep,
    int* __restrict__ hist)
{
    int t = blockIdx.x * 256 + threadIdx.x;
    if (t < NE) atomicAdd(&hist[dst_pe[t]], 1);
    else {
        int e = t - NE;
        if (e < NE) atomicAdd(&hist[N_ENC + dst_ep[e]], 1);
    }
}

__global__ __launch_bounds__(1024) void scan_block_kernel(
    const int* __restrict__ in, int n, int* __restrict__ excl,
    int* __restrict__ partials)
{
    __shared__ int buf[1024];
    int t = threadIdx.x;
    int g = blockIdx.x * 1024 + t;
    int v = (g < n) ? in[g] : 0;
    buf[t] = v;
    __syncthreads();
    for (int off = 1; off < 1024; off <<= 1) {
        int u = (t >= off) ? buf[t - off] : 0;
        __syncthreads();
        buf[t] += u;
        __syncthreads();
    }
    if (g < n) excl[g] = buf[t] - v;
    if (t == 1023) partials[blockIdx.x] = buf[t];
}

__global__ __launch_bounds__(1024) void scan_partials_kernel(
    int* __restrict__ partials, int np)
{
    __shared__ int buf[1024];
    int t = threadIdx.x;
    int v = (t < np) ? partials[t] : 0;
    buf[t] = v;
    __syncthreads();
    for (int off = 1; off < 1024; off <<= 1) {
        int u = (t >= off) ? buf[t - off] : 0;
        __syncthreads();
        buf[t] += u;
        __syncthreads();
    }
    if (t < np) partials[t] = buf[t] - v;
}

__global__ __launch_bounds__(256) void scan_final_kernel(
    const int* __restrict__ excl, const int* __restrict__ partials, int n,
    int total, int* __restrict__ base, int* __restrict__ cur)
{
    int g = blockIdx.x * 256 + threadIdx.x;
    if (g < n) {
        int v = excl[g] + partials[g >> 10];
        base[g] = v;
        cur[g] = v;
    } else if (g == n) {
        base[g] = total;
    }
}

__global__ __launch_bounds__(256) void place_kernel(
    const int* __restrict__ src_pe, const int* __restrict__ dst_pe,
    const int* __restrict__ src_ep, const int* __restrict__ dst_ep,
    int* __restrict__ cur, int* __restrict__ csr)
{
    int t = blockIdx.x * 256 + threadIdx.x;
    int s, d;
    if (t < NE) { s = src_pe[t]; d = dst_pe[t]; }
    else {
        int e = t - NE;
        if (e >= NE) return;
        s = src_ep[e]; d = N_ENC + dst_ep[e];
    }
    int pos = atomicAdd(&cur[d], 1);
    csr[pos] = s;
}

// ---------------- Fused gather + MFMA transform -----------------------------
// One wave = 16 nodes. Lane (m=l&15, q=l>>4) gathers its own A-frag slice
// A[m][k=q*8..q*8+7, 32+q*8..+7] from bf16 source rows over the node's CSR
// edge list. UNROLL edges are processed per iteration with all csr-index
// loads issued first, then all row-gathers (2*UNROLL independent 16B loads
// in flight per lane), then the accumulates — attacks the csr->gather
// dependent-latency chain that R6's counters showed (VALUBusy 29%, hbm 12%).
template <int UNROLL>
__global__ __launch_bounds__(256) void transform_fused_kernel(
    const ushort_t* __restrict__ xsrc, const int* __restrict__ csr,
    const int* __restrict__ base, const ushort_t* __restrict__ xdst,
    const ushort_t* __restrict__ fragWl, const ushort_t* __restrict__ fragWr,
    const float* __restrict__ bias, const float* __restrict__ cvec,
    const float* __restrict__ sval, const float* __restrict__ c0p,
    float* __restrict__ out, int nwaves, int add_extra)
{
    int wid = blockIdx.x * 4 + (threadIdx.x >> 6);
    if (wid >= nwaves) return;
    int l = threadIdx.x & 63;
    int m = l & 15;
    int q = l >> 4;
    int nb = wid * 16;
    int row = nb + m;

    int s0 = base[row], s1 = base[row + 1];
    float degf = (float)(s1 - s0);

    float accf[16];
#pragma unroll
    for (int i = 0; i < 16; i++) accf[i] = 0.f;
    float sa = 0.f;

    int e = s0;
    while (e + UNROLL <= s1) {
        int ss[UNROLL];
#pragma unroll
        for (int u = 0; u < UNROLL; u++) ss[u] = csr[e + u];
        uint4 w0[UNROLL], w1[UNROLL];
#pragma unroll
        for (int u = 0; u < UNROLL; u++) {
            const uint_t* xr = (const uint_t*)(xsrc + (size_t)ss[u] * D);
            w0[u] = *(const uint4*)(xr + q * 4);
            w1[u] = *(const uint4*)(xr + 16 + q * 4);
        }
#pragma unroll
        for (int u = 0; u < UNROLL; u++) {
            uint_t dw[8] = {w0[u].x, w0[u].y, w0[u].z, w0[u].w,
                            w1[u].x, w1[u].y, w1[u].z, w1[u].w};
#pragma unroll
            for (int i = 0; i < 8; i++) {
                accf[2 * i]     += __uint_as_float(dw[i] << 16);
                accf[2 * i + 1] += __uint_as_float(dw[i] & 0xffff0000u);
            }
            if (add_extra) sa += sval[ss[u]];
        }
        e += UNROLL;
    }
    for (; e < s1; e++) {
        int s = csr[e];
        const uint_t* xr = (const uint_t*)(xsrc + (size_t)s * D);
        uint4 w0 = *(const uint4*)(xr + q * 4);
        uint4 w1 = *(const uint4*)(xr + 16 + q * 4);
        uint_t dw[8] = {w0.x, w0.y, w0.z, w0.w, w1.x, w1.y, w1.z, w1.w};
#pragma unroll
        for (int i = 0; i < 8; i++) {
            accf[2 * i]     += __uint_as_float(dw[i] << 16);
            accf[2 * i + 1] += __uint_as_float(dw[i] & 0xffff0000u);
        }
        if (add_extra) sa += sval[s];
    }

    bfrag8 a0, a1;
#pragma unroll
    for (int i = 0; i < 8; i++) {
        a0[i] = (short)f2bf(accf[i]);
        a1[i] = (short)f2bf(accf[8 + i]);
    }

    const ushort_t* xd = xdst + (size_t)row * D;
    bfrag8 x0 = *(const bfrag8*)(xd + q * 8);
    bfrag8 x1 = *(const bfrag8*)(xd + 32 + q * 8);

    f32x4 invc4;
#pragma unroll
    for (int r = 0; r < 4; r++) {
        float dg = __shfl(degf, q * 4 + r);
        invc4[r] = 1.0f / fmaxf(dg, 1.0f);
    }

    float bias_v[8], cvec_v[8];
#pragma unroll
    for (int jt = 0; jt < 8; jt++) {
        bias_v[jt] = bias[jt * 16 + m];
        cvec_v[jt] = cvec[jt * 16 + m];
    }

    f32x4 p = {0.f, 0.f, 0.f, 0.f};
#pragma unroll
    for (int jt = 0; jt < 8; jt++) {
        const bfrag8* bl0 = (const bfrag8*)(fragWl + ((size_t)(jt * 2 + 0) * 64 + l) * 8);
        const bfrag8* bl1 = (const bfrag8*)(fragWl + ((size_t)(jt * 2 + 1) * 64 + l) * 8);
        const bfrag8* br0 = (const bfrag8*)(fragWr + ((size_t)(jt * 2 + 0) * 64 + l) * 8);
        const bfrag8* br1 = (const bfrag8*)(fragWr + ((size_t)(jt * 2 + 1) * 64 + l) * 8);
        f32x4 accl = {0.f, 0.f, 0.f, 0.f};
        f32x4 accr = {0.f, 0.f, 0.f, 0.f};
        accl = __builtin_amdgcn_mfma_f32_16x16x32_bf16(a0, *bl0, accl, 0, 0, 0);
        accl = __builtin_amdgcn_mfma_f32_16x16x32_bf16(a1, *bl1, accl, 0, 0, 0);
        accr = __builtin_amdgcn_mfma_f32_16x16x32_bf16(x0, *br0, accr, 0, 0, 0);
        accr = __builtin_amdgcn_mfma_f32_16x16x32_bf16(x1, *br1, accr, 0, 0, 0);
        float bj = bias_v[jt], cj = cvec_v[jt];
#pragma unroll
        for (int r = 0; r < 4; r++) {
            float z = accl[r] * invc4[r] + accr[r] + bj;
            p[r] += fmaxf(z, 0.f) * cj;
        }
    }
#pragma unroll
    for (int off = 1; off < 16; off <<= 1) {
        p[0] += __shfl_xor(p[0], off, 16);
        p[1] += __shfl_xor(p[1], off, 16);
        p[2] += __shfl_xor(p[2], off, 16);
        p[3] += __shfl_xor(p[3], off, 16);
    }
    f32x4 sa4;
#pragma unroll
    for (int r = 0; r < 4; r++) sa4[r] = __shfl(sa, q * 4 + r);
    if (m == 0) {
        int basen = nb + q * 4;
        f32x4 o = p;
        if (add_extra) {
            float c0 = c0p[0];
#pragma unroll
            for (int r = 0; r < 4; r++)
                o[r] += sa4[r] * invc4[r] + c0;
        }
        *(f32x4*)(out + basen) = o;
    }
}

extern "C" void kernel_launch(void* const* d_in, const int* in_sizes, int n_in,
                              void* d_out, int out_size, void* d_ws, size_t ws_size,
                              hipStream_t stream)
{
    const float* x_enc  = (const float*)d_in[0];
    const float* x_pat  = (const float*)d_in[1];
    const int*   src_pe = (const int*)d_in[2];
    const int*   dst_pe = (const int*)d_in[3];
    const int*   src_ep = (const int*)d_in[4];
    const int*   dst_ep = (const int*)d_in[5];
    const float* Wl_pe1 = (const float*)d_in[6];
    const float* Wr_pe1 = (const float*)d_in[7];
    const float* b_pe1  = (const float*)d_in[8];
    const float* Wl_ep1 = (const float*)d_in[9];
    const float* Wr_ep1 = (const float*)d_in[10];
    const float* b_ep1  = (const float*)d_in[11];
    const float* Wl_pe2 = (const float*)d_in[12];
    const float* Wr_pe2 = (const float*)d_in[13];
    const float* b_pe2  = (const float*)d_in[14];
    const float* Wc = (const float*)d_in[18];
    const float* bc = (const float*)d_in[19];

    float* ws  = (float*)d_ws;
    float* out = (float*)d_out;

    // zero: concatenated histogram only (~2.4 MB)
    hipMemsetAsync(d_ws, 0, (size_t)ZERO_FLOATS * sizeof(float), stream);

    prep_kernel<<<128, 256, 0, stream>>>(Wl_pe1, Wr_pe1, Wl_ep1, Wr_ep1,
                                         Wl_pe2, Wr_pe2, b_pe2, Wc, bc, ws);

    int* hist = (int*)(ws + OFF_HIST);
    int* excl = (int*)(ws + OFF_EXCL);
    int* part = (int*)(ws + OFF_PART);
    int* base = (int*)(ws + OFF_BASE);
    int* cur  = (int*)(ws + OFF_CUR);
    int* csr  = (int*)(ws + OFF_CSR);
    ushort_t* xbf_enc = (ushort_t*)(ws + OFF_XBF_ENC);
    ushort_t* xbf_pat = (ushort_t*)(ws + OFF_XBF_PAT);

    // bf16 feature copies (one launch)
    cvt_bf16_kernel<<<((N_ENC + N_PAT) * D / 8 + 255) / 256, 256, 0, stream>>>(
        x_enc, x_pat, xbf_enc, xbf_pat);

    // CSR build over concatenated node space (one hist, one scan, one place)
    hist_kernel<<<(2 * NE + 255) / 256, 256, 0, stream>>>(dst_pe, dst_ep, hist);

    int nb_all = (N_ALL + 1023) / 1024;   // 587
    scan_block_kernel<<<nb_all, 1024, 0, stream>>>(hist, N_ALL, excl, part);
    scan_partials_kernel<<<1, 1024, 0, stream>>>(part, nb_all);
    scan_final_kernel<<<(N_ALL + 256) / 256, 256, 0, stream>>>(
        excl, part, N_ALL, 2 * NE, base, cur);

    place_kernel<<<(2 * NE + 255) / 256, 256, 0, stream>>>(
        src_pe, dst_pe, src_ep, dst_ep, cur, csr);

    const ushort_t* frags = (const ushort_t*)(ws + OFF_FRAGS);

    // patient transform (fused ep-gather, avg deg 10 -> UNROLL=4) -> s_pat
    int pat_waves = N_PAT / 16;   // 6250
    transform_fused_kernel<4><<<(pat_waves + 3) / 4, 256, 0, stream>>>(
        xbf_enc, csr, base + N_ENC, xbf_pat,
        frags + 2 * 8192, frags + 3 * 8192, b_ep1, ws + OFF_WL2C,
        nullptr, nullptr, ws + OFF_SPAT, pat_waves, 0);

    // encounter transform (fused pe-gather + layer-2 gather, avg deg 2 -> UNROLL=2)
    int enc_waves = N_ENC / 16;   // 31250
    transform_fused_kernel<2><<<(enc_waves + 3) / 4, 256, 0, stream>>>(
        xbf_pat, csr, base, xbf_enc,
        frags + 0 * 8192, frags + 1 * 8192, b_pe1, ws + OFF_WR2C,
        ws + OFF_SPAT, ws + OFF_C0, out, enc_waves, 1);
}